// Round 4
// baseline (475.726 us; speedup 1.0000x reference)
//
#include <hip/hip_runtime.h>
#include <math.h>

#define BATCH 256
#define INDIM 256
#define HDIM  512
#define BH    (BATCH * HDIM)

typedef float f32x4 __attribute__((ext_vector_type(4)));

__device__ __forceinline__ float sigmoidf_(float v) {
    return 1.0f / (1.0f + expf(-v));
}

// ---------------------------------------------------------------------------
// Kernel 1: gates GEMM.  out[g][n][h] = act(sum_k W[h,k] * x[n,k] + b[h])
// M = 6*512 = 3072 (gate rows), N = 256 (batch), K = 256.
// Tiles: 64x64, K-chunks of 64. 256 threads, 4x4 microtile per thread.
//
// LDS: [m][k] layout, stride 68 floats (272 B = 16B-aligned rows) so the
// inner loop reads float4 ALONG K (ds_read_b128: 4x fewer LDS instrs,
// ~2x byte rate vs ds_read_b32 -> LDS-pipe time ~halves; gates kernel is
// LDS-issue-bound at <=1 block/CU).
//   - Xt rows are indexed by ty (4 distinct/wave -> broadcast, conflict-free).
//   - Wt rows are indexed by tx (16 distinct/wave); with a 16B-aligned
//     stride the bank index collapses -> 8-way conflict. Fix: XOR column
//     swizzle col ^= 4*((row>>2)&7) (write and read sides match; preserves
//     float4 contiguity/alignment).
// ---------------------------------------------------------------------------
__global__ __launch_bounds__(256) void gates_kernel(
    const float* __restrict__ x,
    const float* __restrict__ Wq, const float* __restrict__ bq,
    const float* __restrict__ Wk, const float* __restrict__ bk,
    const float* __restrict__ Wv, const float* __restrict__ bv,
    const float* __restrict__ Wi, const float* __restrict__ bi,
    const float* __restrict__ Wf, const float* __restrict__ bf,
    const float* __restrict__ Wo, const float* __restrict__ bo,
    float* __restrict__ gates)
{
    __shared__ float Wt[64][68];
    __shared__ float Xt[64][68];

    const int m0 = blockIdx.x * 64;           // gate-row tile base (0..3071)
    const int n0 = blockIdx.y * 64;           // batch tile base
    const int t  = threadIdx.x;

    const int g  = m0 >> 9;                   // gate index, block-uniform
    const int h0 = m0 & 511;

    const float* W; const float* bias;
    switch (g) {
        case 0: W = Wq; bias = bq; break;
        case 1: W = Wk; bias = bk; break;
        case 2: W = Wv; bias = bv; break;
        case 3: W = Wi; bias = bi; break;
        case 4: W = Wf; bias = bf; break;
        default: W = Wo; bias = bo; break;
    }
    const float* Wg = W + (size_t)h0 * INDIM;

    const int tx = t & 15;                    // h microtile group (4 h each)
    const int ty = t >> 4;                    // n microtile group (4 n each)
    const int xsw = (tx & 7) << 2;            // Wt read-side column swizzle

    float acc[4][4] = {};                     // [n][h]

    for (int k0 = 0; k0 < INDIM; k0 += 64) {
        const int kk4 = (t & 15) * 4;
        const int row = t >> 4;               // 0..15
        #pragma unroll
        for (int rr = 0; rr < 4; rr++) {
            const int mr = row + rr * 16;
            const float4 w = *(const float4*)(Wg + mr * INDIM + k0 + kk4);
            const int wc = kk4 ^ (((mr >> 2) & 7) << 2);
            *(float4*)&Wt[mr][wc] = w;
            const float4 xv = *(const float4*)(x + (n0 + mr) * INDIM + k0 + kk4);
            *(float4*)&Xt[mr][kk4] = xv;
        }
        __syncthreads();
        #pragma unroll
        for (int kk = 0; kk < 64; kk += 4) {
            float4 ax[4], bw[4];
            #pragma unroll
            for (int i2 = 0; i2 < 4; i2++)
                ax[i2] = *(const float4*)&Xt[ty * 4 + i2][kk];
            #pragma unroll
            for (int j = 0; j < 4; j++)
                bw[j] = *(const float4*)&Wt[tx * 4 + j][kk ^ xsw];
            #pragma unroll
            for (int i2 = 0; i2 < 4; i2++)
                #pragma unroll
                for (int j = 0; j < 4; j++)
                    acc[i2][j] += ax[i2].x * bw[j].x + ax[i2].y * bw[j].y
                                + ax[i2].z * bw[j].z + ax[i2].w * bw[j].w;
        }
        __syncthreads();
    }

    const float inv_sqrt_h = 0.044194173824159216f;   // 1/sqrt(512)
    const int hb = h0 + tx * 4;
    const float4 b4 = *(const float4*)(bias + hb);

    #pragma unroll
    for (int i2 = 0; i2 < 4; i2++) {
        const int n = n0 + ty * 4 + i2;
        float4 r;
        r.x = acc[i2][0] + b4.x;
        r.y = acc[i2][1] + b4.y;
        r.z = acc[i2][2] + b4.z;
        r.w = acc[i2][3] + b4.w;
        if (g == 1) {
            r.x *= inv_sqrt_h; r.y *= inv_sqrt_h;
            r.z *= inv_sqrt_h; r.w *= inv_sqrt_h;
        } else if (g == 3) {
            r.x = expf(r.x); r.y = expf(r.y);
            r.z = expf(r.z); r.w = expf(r.w);
        } else if (g >= 4) {
            r.x = sigmoidf_(r.x); r.y = sigmoidf_(r.y);
            r.z = sigmoidf_(r.z); r.w = sigmoidf_(r.w);
        }
        *(float4*)(gates + (size_t)g * BH + (size_t)n * HDIM + hb) = r;
    }
}

// ---------------------------------------------------------------------------
// Kernel 2: the 512 MB pass. Barrier-free, LDS-free. NO min-waves bound
// (round-2's __launch_bounds__(256,4) capped VGPRs at 64 -> spills -> +17us).
//
// C_t[b,r,c] = f[b,c]*C_prev[b,r,c] + v[b,r]*(i[b,c]*k[b,c])
// h_t[b,r]   = o[b,r] * (sum_c C_t[b,r,c]*q[b,c]) / denom[b]
// n_t / denom fused per-wave: each lane's f/i/k/q float4s cover all 512
// columns per wave, so denom comes from a 6-step __shfl_xor butterfly.
//
// Grid: B*16 blocks (32 rows each), 256 threads (4 waves, 8 rows/wave).
// All 16 NT row-loads issued up-front (deep pipeline), then compute +
// NT stores, then all 8 deferred shuffle reductions. (Round-3 verified.)
// ---------------------------------------------------------------------------
__global__ __launch_bounds__(256) void cell_kernel(
    const float* __restrict__ C_prev,
    const float* __restrict__ gates,
    const float* __restrict__ n_prev,
    float* __restrict__ n_out,
    float* __restrict__ C_out,
    float* __restrict__ h_out)
{
    const int blk    = blockIdx.x;
    const int b      = blk >> 4;        // 16 row-chunks per batch
    const int rchunk = blk & 15;
    const int t      = threadIdx.x;
    const int wave   = t >> 6;
    const int lane   = t & 63;

    const float* qb = gates + 0 * (size_t)BH + (size_t)b * HDIM;
    const float* kb = gates + 1 * (size_t)BH + (size_t)b * HDIM;
    const float* vb = gates + 2 * (size_t)BH + (size_t)b * HDIM;
    const float* ib = gates + 3 * (size_t)BH + (size_t)b * HDIM;
    const float* fb = gates + 4 * (size_t)BH + (size_t)b * HDIM;
    const float* ob = gates + 5 * (size_t)BH + (size_t)b * HDIM;
    const float* npv = n_prev + (size_t)b * HDIM;

    const int c0 = lane * 4;            // first float4 (c in [0,256))
    // second float4 at c0 + 256

    const size_t base = (size_t)b * HDIM * HDIM;
    const int r0 = rchunk * 32 + wave * 8;

    // ---- issue the bulk HBM traffic first: all 8 rows, 16 NT float4 loads
    f32x4 cA[8], cB[8];
    #pragma unroll
    for (int rr = 0; rr < 8; rr++) {
        const float* cp = C_prev + base + (size_t)(r0 + rr) * HDIM;
        cA[rr] = __builtin_nontemporal_load((const f32x4*)(cp + c0));
        cB[rr] = __builtin_nontemporal_load((const f32x4*)(cp + 256 + c0));
    }

    // ---- gate vectors (L2/L3-resident, 16 blocks/batch reuse)
    const float4 f0 = *(const float4*)(fb + c0);
    const float4 f1 = *(const float4*)(fb + 256 + c0);
    const float4 q0 = *(const float4*)(qb + c0);
    const float4 q1 = *(const float4*)(qb + 256 + c0);
    const float4 i0 = *(const float4*)(ib + c0);
    const float4 i1 = *(const float4*)(ib + 256 + c0);
    const float4 k0 = *(const float4*)(kb + c0);
    const float4 k1 = *(const float4*)(kb + 256 + c0);

    float4 a0, a1;                      // i*k per c
    a0.x = i0.x * k0.x; a0.y = i0.y * k0.y; a0.z = i0.z * k0.z; a0.w = i0.w * k0.w;
    a1.x = i1.x * k1.x; a1.y = i1.y * k1.y; a1.z = i1.z * k1.z; a1.w = i1.w * k1.w;

    // ---- fused n_t / denom (per-wave, no barriers, no LDS)
    const float4 np0 = *(const float4*)(npv + c0);
    const float4 np1 = *(const float4*)(npv + 256 + c0);
    float4 nt0, nt1;
    nt0.x = f0.x * np0.x + a0.x;  nt0.y = f0.y * np0.y + a0.y;
    nt0.z = f0.z * np0.z + a0.z;  nt0.w = f0.w * np0.w + a0.w;
    nt1.x = f1.x * np1.x + a1.x;  nt1.y = f1.y * np1.y + a1.y;
    nt1.z = f1.z * np1.z + a1.z;  nt1.w = f1.w * np1.w + a1.w;
    if (rchunk == 0 && wave == 0) {
        *(float4*)(n_out + (size_t)b * HDIM + c0)       = nt0;
        *(float4*)(n_out + (size_t)b * HDIM + 256 + c0) = nt1;
    }
    float p = nt0.x * q0.x + nt0.y * q0.y + nt0.z * q0.z + nt0.w * q0.w
            + nt1.x * q1.x + nt1.y * q1.y + nt1.z * q1.z + nt1.w * q1.w;
    #pragma unroll
    for (int off = 32; off > 0; off >>= 1)
        p += __shfl_xor(p, off);
    const float dinv = 1.0f / fmaxf(fabsf(p), 1.0f);

    // ---- per-row broadcasts
    const float4 v4a = *(const float4*)(vb + r0);
    const float4 v4b = *(const float4*)(vb + r0 + 4);
    const float4 o4a = *(const float4*)(ob + r0);
    const float4 o4b = *(const float4*)(ob + r0 + 4);
    const float vr8[8] = {v4a.x, v4a.y, v4a.z, v4a.w, v4b.x, v4b.y, v4b.z, v4b.w};
    const float or8[8] = {o4a.x, o4a.y, o4a.z, o4a.w, o4b.x, o4b.y, o4b.z, o4b.w};

    // ---- compute + NT stores (loads drain in issue order under this)
    float dots[8];
    #pragma unroll
    for (int rr = 0; rr < 8; rr++) {
        const float vr = vr8[rr];

        f32x4 t0, t1;
        t0.x = f0.x * cA[rr].x + vr * a0.x;
        t0.y = f0.y * cA[rr].y + vr * a0.y;
        t0.z = f0.z * cA[rr].z + vr * a0.z;
        t0.w = f0.w * cA[rr].w + vr * a0.w;
        t1.x = f1.x * cB[rr].x + vr * a1.x;
        t1.y = f1.y * cB[rr].y + vr * a1.y;
        t1.z = f1.z * cB[rr].z + vr * a1.z;
        t1.w = f1.w * cB[rr].w + vr * a1.w;

        float* co = C_out + base + (size_t)(r0 + rr) * HDIM;
        __builtin_nontemporal_store(t0, (f32x4*)(co + c0));
        __builtin_nontemporal_store(t1, (f32x4*)(co + 256 + c0));

        dots[rr] = t0.x * q0.x + t0.y * q0.y + t0.z * q0.z + t0.w * q0.w
                 + t1.x * q1.x + t1.y * q1.y + t1.z * q1.z + t1.w * q1.w;
    }

    // ---- deferred reductions (off the store path)
    #pragma unroll
    for (int rr = 0; rr < 8; rr++) {
        float d = dots[rr];
        #pragma unroll
        for (int off = 32; off > 0; off >>= 1)
            d += __shfl_down(d, off);
        if (lane == 0)
            h_out[(size_t)b * HDIM + r0 + rr] = or8[rr] * d * dinv;
    }
}

// ---------------------------------------------------------------------------
extern "C" void kernel_launch(void* const* d_in, const int* in_sizes, int n_in,
                              void* d_out, int out_size, void* d_ws, size_t ws_size,
                              hipStream_t stream) {
    const float* x      = (const float*)d_in[0];
    const float* C_prev = (const float*)d_in[1];
    const float* n_prev = (const float*)d_in[2];
    const float* Wq = (const float*)d_in[3];  const float* bq = (const float*)d_in[4];
    const float* Wk = (const float*)d_in[5];  const float* bk = (const float*)d_in[6];
    const float* Wv = (const float*)d_in[7];  const float* bv = (const float*)d_in[8];
    const float* Wi = (const float*)d_in[9];  const float* bi = (const float*)d_in[10];
    const float* Wf = (const float*)d_in[11]; const float* bf = (const float*)d_in[12];
    const float* Wo = (const float*)d_in[13]; const float* bo = (const float*)d_in[14];

    float* out   = (float*)d_out;
    float* C_out = out;                                    // [B,H,H]
    float* n_out = out + (size_t)BATCH * HDIM * HDIM;      // [B,H]
    float* h_out = n_out + (size_t)BATCH * HDIM;           // [B,H]

    float* gates = (float*)d_ws;                           // 6*B*H floats

    dim3 gridA(3072 / 64, BATCH / 64);                     // 48 x 4
    gates_kernel<<<gridA, 256, 0, stream>>>(x, Wq, bq, Wk, bk, Wv, bv,
                                            Wi, bi, Wf, bf, Wo, bo, gates);
    cell_kernel<<<BATCH * 16, 256, 0, stream>>>(C_prev, gates, n_prev,
                                                n_out, C_out, h_out);
}

// Round 5
// 469.488 us; speedup vs baseline: 1.0133x; 1.0133x over previous
//
#include <hip/hip_runtime.h>
#include <math.h>

#define BATCH 256
#define INDIM 256
#define HDIM  512
#define BH    (BATCH * HDIM)

typedef float f32x4 __attribute__((ext_vector_type(4)));

__device__ __forceinline__ float sigmoidf_(float v) {
    return 1.0f / (1.0f + expf(-v));
}

// ---------------------------------------------------------------------------
// Kernel 1: gates GEMM.  out[g][n][h] = act(sum_k W[h,k] * x[n,k] + b[h])
// M = 6*512 = 3072 (gate rows), N = 256 (batch), K = 256.
// Tiles: 64x64, K-chunks of 64. 256 threads, 4x4 microtile per thread.
//
// Round-1 structure with ONE surgical change: Xt reads go float4-along-k
// (ds_read_b128). Xt rows are indexed by ty (4 distinct rows/wave ->
// 2 start-banks x 2 addresses = 2-way, free per m136), so no swizzle and
// no address XOR is needed (the round-4 Wt-b128+swizzle variant regressed:
// conflicted b128 + inner-loop v_xor). Wt path untouched: scalar b32,
// stride 65 (naturally 2-way). FMA order unchanged -> bit-identical out.
// ---------------------------------------------------------------------------
__global__ __launch_bounds__(256) void gates_kernel(
    const float* __restrict__ x,
    const float* __restrict__ Wq, const float* __restrict__ bq,
    const float* __restrict__ Wk, const float* __restrict__ bk,
    const float* __restrict__ Wv, const float* __restrict__ bv,
    const float* __restrict__ Wi, const float* __restrict__ bi,
    const float* __restrict__ Wf, const float* __restrict__ bf,
    const float* __restrict__ Wo, const float* __restrict__ bo,
    float* __restrict__ gates)
{
    __shared__ float Wt[64][65];
    __shared__ float Xt[64][68];      // stride 68: rows 16B-aligned for b128

    const int m0 = blockIdx.x * 64;           // gate-row tile base (0..3071)
    const int n0 = blockIdx.y * 64;           // batch tile base
    const int t  = threadIdx.x;

    const int g  = m0 >> 9;                   // gate index, block-uniform
    const int h0 = m0 & 511;

    const float* W; const float* bias;
    switch (g) {
        case 0: W = Wq; bias = bq; break;
        case 1: W = Wk; bias = bk; break;
        case 2: W = Wv; bias = bv; break;
        case 3: W = Wi; bias = bi; break;
        case 4: W = Wf; bias = bf; break;
        default: W = Wo; bias = bo; break;
    }
    const float* Wg = W + (size_t)h0 * INDIM;

    const int tx = t & 15;                    // h microtile group (4 h each)
    const int ty = t >> 4;                    // n microtile group (4 n each)

    float acc[4][4] = {};                     // [n][h]

    for (int k0 = 0; k0 < INDIM; k0 += 64) {
        const int kk4 = (t & 15) * 4;
        const int row = t >> 4;               // 0..15
        #pragma unroll
        for (int rr = 0; rr < 4; rr++) {
            const int mr = row + rr * 16;
            const float4 w = *(const float4*)(Wg + mr * INDIM + k0 + kk4);
            Wt[mr][kk4 + 0] = w.x; Wt[mr][kk4 + 1] = w.y;
            Wt[mr][kk4 + 2] = w.z; Wt[mr][kk4 + 3] = w.w;
            const float4 xv = *(const float4*)(x + (n0 + mr) * INDIM + k0 + kk4);
            *(float4*)&Xt[mr][kk4] = xv;      // aligned (row stride 272B)
        }
        __syncthreads();

        #pragma unroll
        for (int kk = 0; kk < 64; kk += 4) {
            float4 ax[4];
            #pragma unroll
            for (int i2 = 0; i2 < 4; i2++)
                ax[i2] = *(const float4*)&Xt[ty * 4 + i2][kk];   // b128, 2-way

            // 4 scalar k-steps against Wt (unchanged round-1 pattern);
            // accumulation order identical to round-1 (kk ascending).
            #define GATES_KSTEP(COMP, KQ)                                   \
            {                                                               \
                float bb[4];                                                \
                _Pragma("unroll")                                           \
                for (int j = 0; j < 4; j++) bb[j] = Wt[tx * 4 + j][kk + KQ];\
                _Pragma("unroll")                                           \
                for (int i2 = 0; i2 < 4; i2++) {                            \
                    _Pragma("unroll")                                       \
                    for (int j = 0; j < 4; j++)                             \
                        acc[i2][j] += ax[i2].COMP * bb[j];                  \
                }                                                           \
            }
            GATES_KSTEP(x, 0)
            GATES_KSTEP(y, 1)
            GATES_KSTEP(z, 2)
            GATES_KSTEP(w, 3)
            #undef GATES_KSTEP
        }
        __syncthreads();
    }

    const float inv_sqrt_h = 0.044194173824159216f;   // 1/sqrt(512)
    const int hb = h0 + tx * 4;
    const float4 b4 = *(const float4*)(bias + hb);

    #pragma unroll
    for (int i2 = 0; i2 < 4; i2++) {
        const int n = n0 + ty * 4 + i2;
        float4 r;
        r.x = acc[i2][0] + b4.x;
        r.y = acc[i2][1] + b4.y;
        r.z = acc[i2][2] + b4.z;
        r.w = acc[i2][3] + b4.w;
        if (g == 1) {
            r.x *= inv_sqrt_h; r.y *= inv_sqrt_h;
            r.z *= inv_sqrt_h; r.w *= inv_sqrt_h;
        } else if (g == 3) {
            r.x = expf(r.x); r.y = expf(r.y);
            r.z = expf(r.z); r.w = expf(r.w);
        } else if (g >= 4) {
            r.x = sigmoidf_(r.x); r.y = sigmoidf_(r.y);
            r.z = sigmoidf_(r.z); r.w = sigmoidf_(r.w);
        }
        *(float4*)(gates + (size_t)g * BH + (size_t)n * HDIM + hb) = r;
    }
}

// ---------------------------------------------------------------------------
// Kernel 2: the 512 MB pass. Barrier-free, LDS-free. NO min-waves bound
// (round-2's __launch_bounds__(256,4) capped VGPRs at 64 -> spills -> +17us).
//
// C_t[b,r,c] = f[b,c]*C_prev[b,r,c] + v[b,r]*(i[b,c]*k[b,c])
// h_t[b,r]   = o[b,r] * (sum_c C_t[b,r,c]*q[b,c]) / denom[b]
// n_t / denom fused per-wave: each lane's f/i/k/q float4s cover all 512
// columns per wave, so denom comes from a 6-step __shfl_xor butterfly.
//
// Grid: B*16 blocks (32 rows each), 256 threads (4 waves, 8 rows/wave).
// All 16 NT row-loads issued up-front (deep pipeline), then compute +
// NT stores, then all 8 deferred shuffle reductions. (Round-3 verified.)
// ---------------------------------------------------------------------------
__global__ __launch_bounds__(256) void cell_kernel(
    const float* __restrict__ C_prev,
    const float* __restrict__ gates,
    const float* __restrict__ n_prev,
    float* __restrict__ n_out,
    float* __restrict__ C_out,
    float* __restrict__ h_out)
{
    const int blk    = blockIdx.x;
    const int b      = blk >> 4;        // 16 row-chunks per batch
    const int rchunk = blk & 15;
    const int t      = threadIdx.x;
    const int wave   = t >> 6;
    const int lane   = t & 63;

    const float* qb = gates + 0 * (size_t)BH + (size_t)b * HDIM;
    const float* kb = gates + 1 * (size_t)BH + (size_t)b * HDIM;
    const float* vb = gates + 2 * (size_t)BH + (size_t)b * HDIM;
    const float* ib = gates + 3 * (size_t)BH + (size_t)b * HDIM;
    const float* fb = gates + 4 * (size_t)BH + (size_t)b * HDIM;
    const float* ob = gates + 5 * (size_t)BH + (size_t)b * HDIM;
    const float* npv = n_prev + (size_t)b * HDIM;

    const int c0 = lane * 4;            // first float4 (c in [0,256))
    // second float4 at c0 + 256

    const size_t base = (size_t)b * HDIM * HDIM;
    const int r0 = rchunk * 32 + wave * 8;

    // ---- issue the bulk HBM traffic first: all 8 rows, 16 NT float4 loads
    f32x4 cA[8], cB[8];
    #pragma unroll
    for (int rr = 0; rr < 8; rr++) {
        const float* cp = C_prev + base + (size_t)(r0 + rr) * HDIM;
        cA[rr] = __builtin_nontemporal_load((const f32x4*)(cp + c0));
        cB[rr] = __builtin_nontemporal_load((const f32x4*)(cp + 256 + c0));
    }

    // ---- gate vectors (L2/L3-resident, 16 blocks/batch reuse)
    const float4 f0 = *(const float4*)(fb + c0);
    const float4 f1 = *(const float4*)(fb + 256 + c0);
    const float4 q0 = *(const float4*)(qb + c0);
    const float4 q1 = *(const float4*)(qb + 256 + c0);
    const float4 i0 = *(const float4*)(ib + c0);
    const float4 i1 = *(const float4*)(ib + 256 + c0);
    const float4 k0 = *(const float4*)(kb + c0);
    const float4 k1 = *(const float4*)(kb + 256 + c0);

    float4 a0, a1;                      // i*k per c
    a0.x = i0.x * k0.x; a0.y = i0.y * k0.y; a0.z = i0.z * k0.z; a0.w = i0.w * k0.w;
    a1.x = i1.x * k1.x; a1.y = i1.y * k1.y; a1.z = i1.z * k1.z; a1.w = i1.w * k1.w;

    // ---- fused n_t / denom (per-wave, no barriers, no LDS)
    const float4 np0 = *(const float4*)(npv + c0);
    const float4 np1 = *(const float4*)(npv + 256 + c0);
    float4 nt0, nt1;
    nt0.x = f0.x * np0.x + a0.x;  nt0.y = f0.y * np0.y + a0.y;
    nt0.z = f0.z * np0.z + a0.z;  nt0.w = f0.w * np0.w + a0.w;
    nt1.x = f1.x * np1.x + a1.x;  nt1.y = f1.y * np1.y + a1.y;
    nt1.z = f1.z * np1.z + a1.z;  nt1.w = f1.w * np1.w + a1.w;
    if (rchunk == 0 && wave == 0) {
        *(float4*)(n_out + (size_t)b * HDIM + c0)       = nt0;
        *(float4*)(n_out + (size_t)b * HDIM + 256 + c0) = nt1;
    }
    float p = nt0.x * q0.x + nt0.y * q0.y + nt0.z * q0.z + nt0.w * q0.w
            + nt1.x * q1.x + nt1.y * q1.y + nt1.z * q1.z + nt1.w * q1.w;
    #pragma unroll
    for (int off = 32; off > 0; off >>= 1)
        p += __shfl_xor(p, off);
    const float dinv = 1.0f / fmaxf(fabsf(p), 1.0f);

    // ---- per-row broadcasts
    const float4 v4a = *(const float4*)(vb + r0);
    const float4 v4b = *(const float4*)(vb + r0 + 4);
    const float4 o4a = *(const float4*)(ob + r0);
    const float4 o4b = *(const float4*)(ob + r0 + 4);
    const float vr8[8] = {v4a.x, v4a.y, v4a.z, v4a.w, v4b.x, v4b.y, v4b.z, v4b.w};
    const float or8[8] = {o4a.x, o4a.y, o4a.z, o4a.w, o4b.x, o4b.y, o4b.z, o4b.w};

    // ---- compute + NT stores (loads drain in issue order under this)
    float dots[8];
    #pragma unroll
    for (int rr = 0; rr < 8; rr++) {
        const float vr = vr8[rr];

        f32x4 t0, t1;
        t0.x = f0.x * cA[rr].x + vr * a0.x;
        t0.y = f0.y * cA[rr].y + vr * a0.y;
        t0.z = f0.z * cA[rr].z + vr * a0.z;
        t0.w = f0.w * cA[rr].w + vr * a0.w;
        t1.x = f1.x * cB[rr].x + vr * a1.x;
        t1.y = f1.y * cB[rr].y + vr * a1.y;
        t1.z = f1.z * cB[rr].z + vr * a1.z;
        t1.w = f1.w * cB[rr].w + vr * a1.w;

        float* co = C_out + base + (size_t)(r0 + rr) * HDIM;
        __builtin_nontemporal_store(t0, (f32x4*)(co + c0));
        __builtin_nontemporal_store(t1, (f32x4*)(co + 256 + c0));

        dots[rr] = t0.x * q0.x + t0.y * q0.y + t0.z * q0.z + t0.w * q0.w
                 + t1.x * q1.x + t1.y * q1.y + t1.z * q1.z + t1.w * q1.w;
    }

    // ---- deferred reductions (off the store path)
    #pragma unroll
    for (int rr = 0; rr < 8; rr++) {
        float d = dots[rr];
        #pragma unroll
        for (int off = 32; off > 0; off >>= 1)
            d += __shfl_down(d, off);
        if (lane == 0)
            h_out[(size_t)b * HDIM + r0 + rr] = or8[rr] * d * dinv;
    }
}

// ---------------------------------------------------------------------------
extern "C" void kernel_launch(void* const* d_in, const int* in_sizes, int n_in,
                              void* d_out, int out_size, void* d_ws, size_t ws_size,
                              hipStream_t stream) {
    const float* x      = (const float*)d_in[0];
    const float* C_prev = (const float*)d_in[1];
    const float* n_prev = (const float*)d_in[2];
    const float* Wq = (const float*)d_in[3];  const float* bq = (const float*)d_in[4];
    const float* Wk = (const float*)d_in[5];  const float* bk = (const float*)d_in[6];
    const float* Wv = (const float*)d_in[7];  const float* bv = (const float*)d_in[8];
    const float* Wi = (const float*)d_in[9];  const float* bi = (const float*)d_in[10];
    const float* Wf = (const float*)d_in[11]; const float* bf = (const float*)d_in[12];
    const float* Wo = (const float*)d_in[13]; const float* bo = (const float*)d_in[14];

    float* out   = (float*)d_out;
    float* C_out = out;                                    // [B,H,H]
    float* n_out = out + (size_t)BATCH * HDIM * HDIM;      // [B,H]
    float* h_out = n_out + (size_t)BATCH * HDIM;           // [B,H]

    float* gates = (float*)d_ws;                           // 6*B*H floats

    dim3 gridA(3072 / 64, BATCH / 64);                     // 48 x 4
    gates_kernel<<<gridA, 256, 0, stream>>>(x, Wq, bq, Wk, bk, Wv, bv,
                                            Wi, bi, Wf, bf, Wo, bo, gates);
    cell_kernel<<<BATCH * 16, 256, 0, stream>>>(C_prev, gates, n_prev,
                                                n_out, C_out, h_out);
}